// Round 3
// baseline (36203.738 us; speedup 1.0000x reference)
//
#include <hip/hip_runtime.h>
#include <stdint.h>

// GRU encoder: VOCAB=50257, EMBED=HIDDEN=1024, SEQ=4096.
// Phase 1: x-projections (parallel GEMMs).
// Phase 2: 4096-step scan, 128 persistent WGs, recurrent weights in VGPRs
//          (launch_bounds(256,1) to prevent the round-1 spill), flag-gated
//          exchanges: plain f32 cells + one release-ordered flag per WG.

#define HID    1024
#define SEQLEN 4096
#define NWG    128
#define RPW    8
#define BLOCK  256

typedef unsigned long long u64;

// ---------------------------------------------------------------------------
// Phase 1: C[t,i] = sum_e emb[seq[t],e] * W[i,e]
// ---------------------------------------------------------------------------
__global__ __launch_bounds__(BLOCK) void proj_gemm(
    const int* __restrict__ seq, const float* __restrict__ emb,
    const float* __restrict__ Wrx, const float* __restrict__ Wzx,
    const float* __restrict__ Wx,
    float* __restrict__ xr, float* __restrict__ xz, float* __restrict__ xh)
{
  __shared__ float As[32][68];
  __shared__ float Bs[32][68];
  __shared__ int   idx[64];

  const float* W = (blockIdx.z == 0) ? Wrx : (blockIdx.z == 1) ? Wzx : Wx;
  float*       C = (blockIdx.z == 0) ? xr  : (blockIdx.z == 1) ? xz  : xh;

  const int tid = threadIdx.x;
  const int t0 = blockIdx.y * 64;
  const int i0 = blockIdx.x * 64;
  if (tid < 64) idx[tid] = seq[t0 + tid];
  __syncthreads();

  float acc[4][4] = {};
  const int tx = tid & 15, ty = tid >> 4;
  const int c4 = (tid & 7) * 4;
  const int r8 = tid >> 3;

  for (int k0 = 0; k0 < HID; k0 += 32) {
    for (int l = 0; l < 2; ++l) {
      const int rr = r8 + l * 32;
      float4 av = *(const float4*)(emb + (size_t)idx[rr] * HID + k0 + c4);
      As[c4+0][rr]=av.x; As[c4+1][rr]=av.y; As[c4+2][rr]=av.z; As[c4+3][rr]=av.w;
      float4 bv = *(const float4*)(W + (size_t)(i0 + rr) * HID + k0 + c4);
      Bs[c4+0][rr]=bv.x; Bs[c4+1][rr]=bv.y; Bs[c4+2][rr]=bv.z; Bs[c4+3][rr]=bv.w;
    }
    __syncthreads();
    #pragma unroll
    for (int k = 0; k < 32; ++k) {
      float a[4], b[4];
      *(float4*)a = *(const float4*)&As[k][ty * 4];
      *(float4*)b = *(const float4*)&Bs[k][tx * 4];
      #pragma unroll
      for (int i = 0; i < 4; ++i)
        #pragma unroll
        for (int j = 0; j < 4; ++j)
          acc[i][j] = fmaf(a[i], b[j], acc[i][j]);
    }
    __syncthreads();
  }
  #pragma unroll
  for (int i = 0; i < 4; ++i) {
    float4 v = make_float4(acc[i][0], acc[i][1], acc[i][2], acc[i][3]);
    *(float4*)(C + (size_t)(t0 + ty * 4 + i) * HID + i0 + tx * 4) = v;
  }
}

// ---------------------------------------------------------------------------
// Coherent data movement.
// Load: asm dwordx4 with sc0 sc1 (bypasses non-coherent L1/L2 -> MALL).
// Store: relaxed agent-scope atomic u64 (2 packed floats) -> lowers to
//        global_store_dwordx2 sc0 sc1. (float4 "v" INPUT constraints don't
//        compile on hipcc -- round-2 lesson -- so stores go via atomics.)
// ---------------------------------------------------------------------------
__device__ __forceinline__ float4 load_f4_coherent(const float* p) {
  float4 v;
  asm volatile("global_load_dwordx4 %0, %1, off sc0 sc1\n\ts_waitcnt vmcnt(0)"
               : "=v"(v) : "v"(p) : "memory");
  return v;
}
__device__ __forceinline__ void store_f2_coherent(float* p, float a, float b) {
  u64 v = ((u64)__float_as_uint(b) << 32) | (u64)__float_as_uint(a);
  __hip_atomic_store((u64*)p, v, __ATOMIC_RELAXED, __HIP_MEMORY_SCOPE_AGENT);
}

// Poll one per-WG flag until it reaches `want`. s_sleep backoff keeps the
// fabric quiet; budget bail-out turns a pathological stall into an absmax
// failure instead of a hang.
__device__ __forceinline__ void poll_flag(const u64* f, u64 want, int* budget) {
  for (;;) {
    u64 v = __hip_atomic_load((u64*)f, __ATOMIC_RELAXED, __HIP_MEMORY_SCOPE_AGENT);
    if (v >= want) break;
    __builtin_amdgcn_s_sleep(1);
    if (--(*budget) <= 0) break;
  }
  asm volatile("" ::: "memory");   // data loads stay after the poll
}

// ---------------------------------------------------------------------------
// Phase 2: persistent scan. WG g owns rows [8g, 8g+8); wave w owns rows
// 8g+2w, 8g+2w+1; lane l covers h-columns {q*256 + 4l + j : q<4, j<4}
// (q-strided: a wave64 ds_read_b128 then hits each bank exactly twice ->
// conflict-free, vs the 32-way conflict of contiguous-16 columns).
// Exchange protocol per publish: each wave's lane0 stores its 2 rows (one
// 8B agent store), __syncthreads drains every thread's store-acks, tid0
// release-stores flag[g]=t. Consumers: thread tid polls flag[tid>>1], then
// one dwordx4 sc0sc1 load of rows [4*tid, 4*tid+4); __syncthreads makes the
// 128-flag AND collective.
// ---------------------------------------------------------------------------
__global__ __launch_bounds__(BLOCK, 1) void rnn_scan(
    const float* __restrict__ Wzh, const float* __restrict__ Wrh,
    const float* __restrict__ Whh,
    const float* __restrict__ xz, const float* __restrict__ xr,
    const float* __restrict__ xh,
    float* __restrict__ hbuf,    // [2][HID]
    float* __restrict__ rhbuf,   // [2][HID]
    u64* __restrict__ fh,        // [NWG]
    u64* __restrict__ frh,       // [NWG]
    float* __restrict__ out)
{
  const int tid  = threadIdx.x;
  const int wave = tid >> 6, lane = tid & 63;
  const int g    = blockIdx.x;
  const int r0   = g * RPW;
  const int rowA = r0 + wave * 2;
  const int j0   = tid * 4;          // this thread's 4 exchange rows
  const int src  = tid >> 1;         // WG that produces rows [j0, j0+4)

  __shared__ float h_lds[HID];
  __shared__ float rh_lds[HID];

  // Weights in VGPRs: wgt[m][rr][q*4+j] = Wm[rowA+rr][q*256 + 4*lane + j]
  float wgt[3][2][16];
  #pragma unroll
  for (int m = 0; m < 3; ++m) {
    const float* Wm = (m == 0) ? Wzh : (m == 1) ? Wrh : Whh;
    #pragma unroll
    for (int rr = 0; rr < 2; ++rr) {
      const float* p = Wm + (size_t)(rowA + rr) * HID + lane * 4;
      #pragma unroll
      for (int q = 0; q < 4; ++q) {
        float4 v = *(const float4*)(p + q * 256);
        wgt[m][rr][q*4+0] = v.x; wgt[m][rr][q*4+1] = v.y;
        wgt[m][rr][q*4+2] = v.z; wgt[m][rr][q*4+3] = v.w;
      }
    }
  }

  int budget = 1 << 22;
  float xzv[2], xrv[2], xhv[2], zv[2], hprev[2];

  for (int t = 1; t <= SEQLEN; ++t) {
    // x-projection rows for this step (independent; overlap with the poll).
    if (lane == 0) {
      #pragma unroll
      for (int rr = 0; rr < 2; ++rr) {
        xzv[rr] = xz[(size_t)(t - 1) * HID + rowA + rr];
        xrv[rr] = xr[(size_t)(t - 1) * HID + rowA + rr];
        xhv[rr] = xh[(size_t)(t - 1) * HID + rowA + rr];
      }
    }

    // ---- exchange 1: h_{t-1} ----
    if (t == 1) {
      *(float4*)&h_lds[j0] = make_float4(0.f, 0.f, 0.f, 0.f);
    } else {
      poll_flag(&fh[src], (u64)(t - 1), &budget);
      float4 hv = load_f4_coherent(hbuf + ((t - 1) & 1) * HID + j0);
      *(float4*)&h_lds[j0] = hv;
    }
    __syncthreads();                                   // [B1]

    // gate dots over this lane's strided 16 columns, then 64-lane reduce.
    float hr[16];
    #pragma unroll
    for (int q = 0; q < 4; ++q)
      *(float4*)&hr[q*4] = *(const float4*)&h_lds[q * 256 + lane * 4];
    float az[2] = {0.f, 0.f}, ar[2] = {0.f, 0.f};
    #pragma unroll
    for (int rr = 0; rr < 2; ++rr)
      #pragma unroll
      for (int c = 0; c < 16; ++c) {
        az[rr] = fmaf(wgt[0][rr][c], hr[c], az[rr]);
        ar[rr] = fmaf(wgt[1][rr][c], hr[c], ar[rr]);
      }
    #pragma unroll
    for (int m = 1; m < 64; m <<= 1) {
      az[0] += __shfl_xor(az[0], m, 64);
      az[1] += __shfl_xor(az[1], m, 64);
      ar[0] += __shfl_xor(ar[0], m, 64);
      ar[1] += __shfl_xor(ar[1], m, 64);
    }
    if (lane == 0) {
      float rh[2];
      #pragma unroll
      for (int rr = 0; rr < 2; ++rr) {
        hprev[rr] = h_lds[rowA + rr];
        zv[rr]    = 1.f / (1.f + __expf(-(xzv[rr] + az[rr])));
        float rg  = 1.f / (1.f + __expf(-(xrv[rr] + ar[rr])));
        rh[rr]    = rg * hprev[rr];
      }
      store_f2_coherent(rhbuf + (t & 1) * HID + rowA, rh[0], rh[1]);
    }
    __syncthreads();                                   // [B2] drains store-acks
    if (tid == 0)
      __hip_atomic_store(&frh[g], (u64)t, __ATOMIC_RELEASE, __HIP_MEMORY_SCOPE_AGENT);

    // ---- exchange 2: (r*h)_t ----
    poll_flag(&frh[src], (u64)t, &budget);
    {
      float4 rv = load_f4_coherent(rhbuf + (t & 1) * HID + j0);
      *(float4*)&rh_lds[j0] = rv;
    }
    __syncthreads();                                   // [B3]

    float rr16[16];
    #pragma unroll
    for (int q = 0; q < 4; ++q)
      *(float4*)&rr16[q*4] = *(const float4*)&rh_lds[q * 256 + lane * 4];
    float ac[2] = {0.f, 0.f};
    #pragma unroll
    for (int rr = 0; rr < 2; ++rr)
      #pragma unroll
      for (int c = 0; c < 16; ++c)
        ac[rr] = fmaf(wgt[2][rr][c], rr16[c], ac[rr]);
    #pragma unroll
    for (int m = 1; m < 64; m <<= 1) {
      ac[0] += __shfl_xor(ac[0], m, 64);
      ac[1] += __shfl_xor(ac[1], m, 64);
    }
    if (lane == 0) {
      float hn[2];
      #pragma unroll
      for (int rr = 0; rr < 2; ++rr) {
        float cand = tanhf(xhv[rr] + ac[rr]);
        hn[rr]     = zv[rr] * hprev[rr] + (1.f - zv[rr]) * cand;
      }
      store_f2_coherent(hbuf + (t & 1) * HID + rowA, hn[0], hn[1]);
      if (t == SEQLEN) { out[rowA] = hn[0]; out[rowA + 1] = hn[1]; }
    }
    __syncthreads();                                   // [B4] drains store-acks
    if (tid == 0)
      __hip_atomic_store(&fh[g], (u64)t, __ATOMIC_RELEASE, __HIP_MEMORY_SCOPE_AGENT);
  }
}

// ---------------------------------------------------------------------------
extern "C" void kernel_launch(void* const* d_in, const int* in_sizes, int n_in,
                              void* d_out, int out_size, void* d_ws, size_t ws_size,
                              hipStream_t stream) {
  (void)in_sizes; (void)n_in; (void)out_size; (void)ws_size;

  const int*   seq = (const int*)d_in[0];
  const float* emb = (const float*)d_in[1];
  const float* Wrx = (const float*)d_in[2];
  const float* Wrh = (const float*)d_in[3];
  const float* Wzx = (const float*)d_in[4];
  const float* Wzh = (const float*)d_in[5];
  const float* Wx  = (const float*)d_in[6];
  const float* Wh  = (const float*)d_in[7];

  char* ws = (char*)d_ws;
  const size_t PROJ = (size_t)SEQLEN * HID * sizeof(float);   // 16 MB each
  float* xr    = (float*)(ws);
  float* xz    = (float*)(ws + PROJ);
  float* xh    = (float*)(ws + 2 * PROJ);
  float* hbuf  = (float*)(ws + 3 * PROJ);                     // [2][HID]
  float* rhbuf = (float*)(ws + 3 * PROJ + 2 * HID * sizeof(float));
  u64*   fh    = (u64*)  (ws + 3 * PROJ + 4 * HID * sizeof(float));
  u64*   frh   = fh + NWG;

  // Flags reset every launch (replay-safe; data reads are flag-gated).
  (void)hipMemsetAsync(fh, 0, 2 * NWG * sizeof(u64), stream);

  proj_gemm<<<dim3(HID / 64, SEQLEN / 64, 3), BLOCK, 0, stream>>>(
      seq, emb, Wrx, Wzx, Wx, xr, xz, xh);

  rnn_scan<<<dim3(NWG), BLOCK, 0, stream>>>(
      Wzh, Wrh, Wh, xz, xr, xh, hbuf, rhbuf, fh, frh, (float*)d_out);
}

// Round 4
// 24626.970 us; speedup vs baseline: 1.4701x; 1.4701x over previous
//
#include <hip/hip_runtime.h>
#include <stdint.h>

// GRU encoder: VOCAB=50257, EMBED=HIDDEN=1024, SEQ=4096.
// Phase 1: x-projections (parallel GEMMs).
// Phase 2: 4096-step scan, 128 persistent WGs. Exchange protocol = fused
//          (tag|value) 64-bit cells: ONE MALL visibility event per exchange
//          (round-3 lesson: flag indirection = 3-4 serialized round trips).
//          Consumers poll with two coalesced 16B loads, tags ride in .y/.w.

#define HID    1024
#define SEQLEN 4096
#define NWG    128
#define RPW    8
#define BLOCK  256

typedef unsigned long long u64;

// ---------------------------------------------------------------------------
// Phase 1: C[t,i] = sum_e emb[seq[t],e] * W[i,e]
// ---------------------------------------------------------------------------
__global__ __launch_bounds__(BLOCK) void proj_gemm(
    const int* __restrict__ seq, const float* __restrict__ emb,
    const float* __restrict__ Wrx, const float* __restrict__ Wzx,
    const float* __restrict__ Wx,
    float* __restrict__ xr, float* __restrict__ xz, float* __restrict__ xh)
{
  __shared__ float As[32][68];
  __shared__ float Bs[32][68];
  __shared__ int   idx[64];

  const float* W = (blockIdx.z == 0) ? Wrx : (blockIdx.z == 1) ? Wzx : Wx;
  float*       C = (blockIdx.z == 0) ? xr  : (blockIdx.z == 1) ? xz  : xh;

  const int tid = threadIdx.x;
  const int t0 = blockIdx.y * 64;
  const int i0 = blockIdx.x * 64;
  if (tid < 64) idx[tid] = seq[t0 + tid];
  __syncthreads();

  float acc[4][4] = {};
  const int tx = tid & 15, ty = tid >> 4;
  const int c4 = (tid & 7) * 4;
  const int r8 = tid >> 3;

  for (int k0 = 0; k0 < HID; k0 += 32) {
    for (int l = 0; l < 2; ++l) {
      const int rr = r8 + l * 32;
      float4 av = *(const float4*)(emb + (size_t)idx[rr] * HID + k0 + c4);
      As[c4+0][rr]=av.x; As[c4+1][rr]=av.y; As[c4+2][rr]=av.z; As[c4+3][rr]=av.w;
      float4 bv = *(const float4*)(W + (size_t)(i0 + rr) * HID + k0 + c4);
      Bs[c4+0][rr]=bv.x; Bs[c4+1][rr]=bv.y; Bs[c4+2][rr]=bv.z; Bs[c4+3][rr]=bv.w;
    }
    __syncthreads();
    #pragma unroll
    for (int k = 0; k < 32; ++k) {
      float a[4], b[4];
      *(float4*)a = *(const float4*)&As[k][ty * 4];
      *(float4*)b = *(const float4*)&Bs[k][tx * 4];
      #pragma unroll
      for (int i = 0; i < 4; ++i)
        #pragma unroll
        for (int j = 0; j < 4; ++j)
          acc[i][j] = fmaf(a[i], b[j], acc[i][j]);
    }
    __syncthreads();
  }
  #pragma unroll
  for (int i = 0; i < 4; ++i) {
    float4 v = make_float4(acc[i][0], acc[i][1], acc[i][2], acc[i][3]);
    *(float4*)(C + (size_t)(t0 + ty * 4 + i) * HID + i0 + tx * 4) = v;
  }
}

// ---------------------------------------------------------------------------
// Fused-cell exchange primitives.
// Cell = u64: low 32 = f32 value bits, high 32 = step tag. A 16B coherent
// load returns {val0,tag0,val1,tag1} in {x,y,z,w} -- tag+data in one event.
// ---------------------------------------------------------------------------
__device__ __forceinline__ void load2_f4_coherent(const float* p0, const float* p1,
                                                  float4* a, float4* b) {
  float4 va, vb;
  asm volatile("global_load_dwordx4 %0, %2, off sc0 sc1\n\t"
               "global_load_dwordx4 %1, %3, off sc0 sc1\n\t"
               "s_waitcnt vmcnt(0)"
               : "=&v"(va), "=&v"(vb) : "v"(p0), "v"(p1) : "memory");
  *a = va; *b = vb;
}

__device__ __forceinline__ void publish2(u64* cells, int row, float a, float b,
                                         unsigned tag) {
  u64 ca = ((u64)tag << 32) | (u64)__float_as_uint(a);
  u64 cb = ((u64)tag << 32) | (u64)__float_as_uint(b);
  __hip_atomic_store(&cells[row],     ca, __ATOMIC_RELAXED, __HIP_MEMORY_SCOPE_AGENT);
  __hip_atomic_store(&cells[row + 1], cb, __ATOMIC_RELAXED, __HIP_MEMORY_SCOPE_AGENT);
}

// Poll this thread's 4 cells (2 coalesced 16B loads/round) until all tags
// match `want`, then drop the 4 values into dst_lds. Budget bail-out turns
// a pathological stall into an absmax failure instead of a hang.
__device__ __forceinline__ void exchange_read(const u64* cells, unsigned want,
                                              float* dst_lds, int wave, int lane,
                                              int* budget) {
  const int c0 = wave * 256 + 2 * lane;    // cells c0, c0+1
  const int c1 = c0 + 128;                 // cells c1, c1+1
  const float* p0 = (const float*)(cells + c0);
  const float* p1 = (const float*)(cells + c1);
  float4 v0, v1;
  for (;;) {
    load2_f4_coherent(p0, p1, &v0, &v1);
    if (__float_as_uint(v0.y) == want && __float_as_uint(v0.w) == want &&
        __float_as_uint(v1.y) == want && __float_as_uint(v1.w) == want) break;
    if (--(*budget) <= 0) break;
  }
  *(float2*)&dst_lds[c0] = make_float2(v0.x, v0.z);
  *(float2*)&dst_lds[c1] = make_float2(v1.x, v1.z);
}

// ---------------------------------------------------------------------------
// Phase 2: persistent scan. WG g owns rows [8g, 8g+8); wave w owns rows
// 8g+2w, 8g+2w+1; lane l covers h-columns {q*256 + 4l + j} (q-strided,
// conflict-free). Per step: poll h cells -> B1 -> gates -> lane0 publishes
// r*h cells (fused tag) -> poll rh cells -> B2 -> candidate -> lane0
// publishes h cells. Only 2 barriers and 2 visibility events per step.
// ---------------------------------------------------------------------------
__global__ __launch_bounds__(BLOCK, 1) void rnn_scan(
    const float* __restrict__ Wzh, const float* __restrict__ Wrh,
    const float* __restrict__ Whh,
    const float* __restrict__ xz, const float* __restrict__ xr,
    const float* __restrict__ xh,
    u64* __restrict__ hcell,     // [2][HID]
    u64* __restrict__ rhcell,    // [2][HID]
    float* __restrict__ out)
{
  const int tid  = threadIdx.x;
  const int wave = tid >> 6, lane = tid & 63;
  const int g    = blockIdx.x;
  const int rowA = g * RPW + wave * 2;

  __shared__ float h_lds[HID];
  __shared__ float rh_lds[HID];

  // Weights: wgt[m][rr][q*4+j] = Wm[rowA+rr][q*256 + 4*lane + j].
  // (May land in AGPRs -- round-3 lesson: that's register-speed, fine.)
  float wgt[3][2][16];
  #pragma unroll
  for (int m = 0; m < 3; ++m) {
    const float* Wm = (m == 0) ? Wzh : (m == 1) ? Wrh : Whh;
    #pragma unroll
    for (int rr = 0; rr < 2; ++rr) {
      const float* p = Wm + (size_t)(rowA + rr) * HID + lane * 4;
      #pragma unroll
      for (int q = 0; q < 4; ++q) {
        float4 v = *(const float4*)(p + q * 256);
        wgt[m][rr][q*4+0] = v.x; wgt[m][rr][q*4+1] = v.y;
        wgt[m][rr][q*4+2] = v.z; wgt[m][rr][q*4+3] = v.w;
      }
    }
  }

  int budget = 1 << 22;
  float xzv[2], xrv[2], xhv[2], zv[2], hprev[2];

  for (int t = 1; t <= SEQLEN; ++t) {
    // x-projection rows for this step (independent; overlaps the h poll).
    if (lane == 0) {
      #pragma unroll
      for (int rr = 0; rr < 2; ++rr) {
        xzv[rr] = xz[(size_t)(t - 1) * HID + rowA + rr];
        xrv[rr] = xr[(size_t)(t - 1) * HID + rowA + rr];
        xhv[rr] = xh[(size_t)(t - 1) * HID + rowA + rr];
      }
    }

    // ---- exchange 1: h_{t-1} (tag t-1, parity (t-1)&1) ----
    if (t == 1) {
      const int c0 = wave * 256 + 2 * lane, c1 = c0 + 128;
      *(float2*)&h_lds[c0] = make_float2(0.f, 0.f);
      *(float2*)&h_lds[c1] = make_float2(0.f, 0.f);
    } else {
      exchange_read(hcell + ((t - 1) & 1) * HID, (unsigned)(t - 1),
                    h_lds, wave, lane, &budget);
    }
    __syncthreads();                                   // [B1]

    // gate dots over q-strided 16 columns, 64-lane shuffle reduce.
    float hr[16];
    #pragma unroll
    for (int q = 0; q < 4; ++q)
      *(float4*)&hr[q*4] = *(const float4*)&h_lds[q * 256 + lane * 4];
    float az[2] = {0.f, 0.f}, ar[2] = {0.f, 0.f};
    #pragma unroll
    for (int rr = 0; rr < 2; ++rr)
      #pragma unroll
      for (int c = 0; c < 16; ++c) {
        az[rr] = fmaf(wgt[0][rr][c], hr[c], az[rr]);
        ar[rr] = fmaf(wgt[1][rr][c], hr[c], ar[rr]);
      }
    #pragma unroll
    for (int m = 1; m < 64; m <<= 1) {
      az[0] += __shfl_xor(az[0], m, 64);
      az[1] += __shfl_xor(az[1], m, 64);
      ar[0] += __shfl_xor(ar[0], m, 64);
      ar[1] += __shfl_xor(ar[1], m, 64);
    }
    if (lane == 0) {
      float rh[2];
      #pragma unroll
      for (int rr = 0; rr < 2; ++rr) {
        hprev[rr] = h_lds[rowA + rr];
        zv[rr]    = 1.f / (1.f + __expf(-(xzv[rr] + az[rr])));
        float rg  = 1.f / (1.f + __expf(-(xrv[rr] + ar[rr])));
        rh[rr]    = rg * hprev[rr];
      }
      publish2(rhcell + (t & 1) * HID, rowA, rh[0], rh[1], (unsigned)t);
    }

    // ---- exchange 2: (r*h)_t (tag t, parity t&1) ----
    exchange_read(rhcell + (t & 1) * HID, (unsigned)t, rh_lds, wave, lane, &budget);
    __syncthreads();                                   // [B2]

    float rr16[16];
    #pragma unroll
    for (int q = 0; q < 4; ++q)
      *(float4*)&rr16[q*4] = *(const float4*)&rh_lds[q * 256 + lane * 4];
    float ac[2] = {0.f, 0.f};
    #pragma unroll
    for (int rr = 0; rr < 2; ++rr)
      #pragma unroll
      for (int c = 0; c < 16; ++c)
        ac[rr] = fmaf(wgt[2][rr][c], rr16[c], ac[rr]);
    #pragma unroll
    for (int m = 1; m < 64; m <<= 1) {
      ac[0] += __shfl_xor(ac[0], m, 64);
      ac[1] += __shfl_xor(ac[1], m, 64);
    }
    if (lane == 0) {
      float hn[2];
      #pragma unroll
      for (int rr = 0; rr < 2; ++rr) {
        float cand = tanhf(xhv[rr] + ac[rr]);
        hn[rr]     = zv[rr] * hprev[rr] + (1.f - zv[rr]) * cand;
      }
      publish2(hcell + (t & 1) * HID, rowA, hn[0], hn[1], (unsigned)t);
      if (t == SEQLEN) { out[rowA] = hn[0]; out[rowA + 1] = hn[1]; }
    }
  }
}

// ---------------------------------------------------------------------------
extern "C" void kernel_launch(void* const* d_in, const int* in_sizes, int n_in,
                              void* d_out, int out_size, void* d_ws, size_t ws_size,
                              hipStream_t stream) {
  (void)in_sizes; (void)n_in; (void)out_size; (void)ws_size;

  const int*   seq = (const int*)d_in[0];
  const float* emb = (const float*)d_in[1];
  const float* Wrx = (const float*)d_in[2];
  const float* Wrh = (const float*)d_in[3];
  const float* Wzx = (const float*)d_in[4];
  const float* Wzh = (const float*)d_in[5];
  const float* Wx  = (const float*)d_in[6];
  const float* Wh  = (const float*)d_in[7];

  char* ws = (char*)d_ws;
  const size_t PROJ = (size_t)SEQLEN * HID * sizeof(float);   // 16 MB each
  float* xr    = (float*)(ws);
  float* xz    = (float*)(ws + PROJ);
  float* xh    = (float*)(ws + 2 * PROJ);
  u64*   hcell = (u64*)(ws + 3 * PROJ);                       // [2][HID]
  u64*   rhcell= hcell + 2 * HID;                             // [2][HID]

  // Tag reset every launch: 0xFFFFFFFF never matches a wanted tag in [1,4096].
  // (Replay-safe: consumers must wait for THIS launch's producers.)
  (void)hipMemsetAsync(hcell, 0xFF, 4 * HID * sizeof(u64), stream);

  proj_gemm<<<dim3(HID / 64, SEQLEN / 64, 3), BLOCK, 0, stream>>>(
      seq, emb, Wrx, Wzx, Wx, xr, xz, xh);

  rnn_scan<<<dim3(NWG), BLOCK, 0, stream>>>(
      Wzh, Wrh, Wh, xz, xr, xh, hcell, rhcell, (float*)d_out);
}

// Round 5
// 24052.155 us; speedup vs baseline: 1.5052x; 1.0239x over previous
//
#include <hip/hip_runtime.h>
#include <stdint.h>

// GRU encoder: VOCAB=50257, EMBED=HIDDEN=1024, SEQ=4096.
// Phase 1: x-projections (parallel GEMMs).
// Phase 2: 4096-step scan, 64 persistent WGs x 512 threads (round-5 change:
//          halves poll congestion vs 128x256; each consumer thread polls
//          exactly ONE 16B fused (tag|value) cell-pair that one producer
//          wrote with two back-to-back 8B agent stores).

#define HID    1024
#define SEQLEN 4096
#define NWG    64
#define RPW    16      // hidden rows per WG
#define BLOCK  512     // 8 waves; wave w owns rows 16g+2w, 16g+2w+1

typedef unsigned long long u64;

// ---------------------------------------------------------------------------
// Phase 1: C[t,i] = sum_e emb[seq[t],e] * W[i,e]   (block 256, 64x64 tile)
// ---------------------------------------------------------------------------
__global__ __launch_bounds__(256) void proj_gemm(
    const int* __restrict__ seq, const float* __restrict__ emb,
    const float* __restrict__ Wrx, const float* __restrict__ Wzx,
    const float* __restrict__ Wx,
    float* __restrict__ xr, float* __restrict__ xz, float* __restrict__ xh)
{
  __shared__ float As[32][68];
  __shared__ float Bs[32][68];
  __shared__ int   idx[64];

  const float* W = (blockIdx.z == 0) ? Wrx : (blockIdx.z == 1) ? Wzx : Wx;
  float*       C = (blockIdx.z == 0) ? xr  : (blockIdx.z == 1) ? xz  : xh;

  const int tid = threadIdx.x;
  const int t0 = blockIdx.y * 64;
  const int i0 = blockIdx.x * 64;
  if (tid < 64) idx[tid] = seq[t0 + tid];
  __syncthreads();

  float acc[4][4] = {};
  const int tx = tid & 15, ty = tid >> 4;
  const int c4 = (tid & 7) * 4;
  const int r8 = tid >> 3;

  for (int k0 = 0; k0 < HID; k0 += 32) {
    for (int l = 0; l < 2; ++l) {
      const int rr = r8 + l * 32;
      float4 av = *(const float4*)(emb + (size_t)idx[rr] * HID + k0 + c4);
      As[c4+0][rr]=av.x; As[c4+1][rr]=av.y; As[c4+2][rr]=av.z; As[c4+3][rr]=av.w;
      float4 bv = *(const float4*)(W + (size_t)(i0 + rr) * HID + k0 + c4);
      Bs[c4+0][rr]=bv.x; Bs[c4+1][rr]=bv.y; Bs[c4+2][rr]=bv.z; Bs[c4+3][rr]=bv.w;
    }
    __syncthreads();
    #pragma unroll
    for (int k = 0; k < 32; ++k) {
      float a[4], b[4];
      *(float4*)a = *(const float4*)&As[k][ty * 4];
      *(float4*)b = *(const float4*)&Bs[k][tx * 4];
      #pragma unroll
      for (int i = 0; i < 4; ++i)
        #pragma unroll
        for (int j = 0; j < 4; ++j)
          acc[i][j] = fmaf(a[i], b[j], acc[i][j]);
    }
    __syncthreads();
  }
  #pragma unroll
  for (int i = 0; i < 4; ++i) {
    float4 v = make_float4(acc[i][0], acc[i][1], acc[i][2], acc[i][3]);
    *(float4*)(C + (size_t)(t0 + ty * 4 + i) * HID + i0 + tx * 4) = v;
  }
}

// ---------------------------------------------------------------------------
// Fused-cell primitives. Cell = u64 {low: f32 bits, high: step tag}.
// Consumer: one 16B sc0sc1 load returns {val0,tag0,val1,tag1}; tag+data in
// one visibility event. Torn producer stores are safe: a stale tag on one
// half just retries.
// ---------------------------------------------------------------------------
__device__ __forceinline__ void publish2(u64* cells, int row, float a, float b,
                                         unsigned tag) {
  u64 ca = ((u64)tag << 32) | (u64)__float_as_uint(a);
  u64 cb = ((u64)tag << 32) | (u64)__float_as_uint(b);
  __hip_atomic_store(&cells[row],     ca, __ATOMIC_RELAXED, __HIP_MEMORY_SCOPE_AGENT);
  __hip_atomic_store(&cells[row + 1], cb, __ATOMIC_RELAXED, __HIP_MEMORY_SCOPE_AGENT);
}

// Poll ONE 16B cell-pair until both tags == want. Nothing is left in flight
// at exit (the load asm embeds its own vmcnt(0)) -- no dangling-register
// hazard. Budget bail-out turns pathological stalls into an absmax fail.
__device__ __forceinline__ float2 poll_pair(const u64* cells, int pair,
                                            unsigned want, int* budget) {
  const float* p = (const float*)(cells + 2 * pair);
  float4 v;
  for (;;) {
    asm volatile("global_load_dwordx4 %0, %1, off sc0 sc1\n\ts_waitcnt vmcnt(0)"
                 : "=v"(v) : "v"(p) : "memory");
    if (__float_as_uint(v.y) == want && __float_as_uint(v.w) == want) break;
    if (--(*budget) <= 0) break;
  }
  return make_float2(v.x, v.z);
}

// ---------------------------------------------------------------------------
// Phase 2: persistent scan. WG g owns rows [16g,16g+16); wave w (of 8) owns
// rows 16g+2w, +1; lane l covers h-columns {q*256+4l+j} (q-strided,
// conflict-free LDS reads). Consumer thread tid polls rows {2tid, 2tid+1}.
// Per step: poll h -> B1 -> gates -> publish r*h -> poll rh -> B2 ->
// candidate -> publish h. 2 visibility events, 2 barriers per step.
// ---------------------------------------------------------------------------
__global__ __launch_bounds__(BLOCK, 2) void rnn_scan(
    const float* __restrict__ Wzh, const float* __restrict__ Wrh,
    const float* __restrict__ Whh,
    const float* __restrict__ xz, const float* __restrict__ xr,
    const float* __restrict__ xh,
    u64* __restrict__ hcell,     // [2][HID]
    u64* __restrict__ rhcell,    // [2][HID]
    float* __restrict__ out)
{
  const int tid  = threadIdx.x;
  const int wave = tid >> 6, lane = tid & 63;
  const int g    = blockIdx.x;
  const int rowA = g * RPW + wave * 2;

  __shared__ float h_lds[HID];
  __shared__ float rh_lds[HID];

  // Weights: wgt[m][rr][q*4+j] = Wm[rowA+rr][q*256 + 4*lane + j].
  float wgt[3][2][16];
  #pragma unroll
  for (int m = 0; m < 3; ++m) {
    const float* Wm = (m == 0) ? Wzh : (m == 1) ? Wrh : Whh;
    #pragma unroll
    for (int rr = 0; rr < 2; ++rr) {
      const float* p = Wm + (size_t)(rowA + rr) * HID + lane * 4;
      #pragma unroll
      for (int q = 0; q < 4; ++q) {
        float4 v = *(const float4*)(p + q * 256);
        wgt[m][rr][q*4+0] = v.x; wgt[m][rr][q*4+1] = v.y;
        wgt[m][rr][q*4+2] = v.z; wgt[m][rr][q*4+3] = v.w;
      }
    }
  }

  int budget = 1 << 21;
  float xzv[2], xrv[2], xhv[2], zv[2], hprev[2];

  for (int t = 1; t <= SEQLEN; ++t) {
    // ---- exchange 1: h_{t-1} (tag t-1, parity (t-1)&1) ----
    if (t == 1) {
      *(float2*)&h_lds[2 * tid] = make_float2(0.f, 0.f);
    } else {
      float2 hv = poll_pair(hcell + ((t - 1) & 1) * HID, tid,
                            (unsigned)(t - 1), &budget);
      *(float2*)&h_lds[2 * tid] = hv;
    }

    // x-projection rows for this step: issued post-poll, latency hides
    // under the barrier wait + gate matvec (round-5: keeps the poll's
    // vmcnt window clean).
    if (lane == 0) {
      #pragma unroll
      for (int rr = 0; rr < 2; ++rr) {
        xzv[rr] = xz[(size_t)(t - 1) * HID + rowA + rr];
        xrv[rr] = xr[(size_t)(t - 1) * HID + rowA + rr];
        xhv[rr] = xh[(size_t)(t - 1) * HID + rowA + rr];
      }
    }
    __syncthreads();                                   // [B1]

    // gate dots over q-strided 16 columns, 64-lane shuffle reduce.
    float hr[16];
    #pragma unroll
    for (int q = 0; q < 4; ++q)
      *(float4*)&hr[q*4] = *(const float4*)&h_lds[q * 256 + lane * 4];
    float az[2] = {0.f, 0.f}, ar[2] = {0.f, 0.f};
    #pragma unroll
    for (int rr = 0; rr < 2; ++rr)
      #pragma unroll
      for (int c = 0; c < 16; ++c) {
        az[rr] = fmaf(wgt[0][rr][c], hr[c], az[rr]);
        ar[rr] = fmaf(wgt[1][rr][c], hr[c], ar[rr]);
      }
    #pragma unroll
    for (int m = 1; m < 64; m <<= 1) {
      az[0] += __shfl_xor(az[0], m, 64);
      az[1] += __shfl_xor(az[1], m, 64);
      ar[0] += __shfl_xor(ar[0], m, 64);
      ar[1] += __shfl_xor(ar[1], m, 64);
    }
    if (lane == 0) {
      float rh[2];
      #pragma unroll
      for (int rr = 0; rr < 2; ++rr) {
        hprev[rr] = h_lds[rowA + rr];
        zv[rr]    = 1.f / (1.f + __expf(-(xzv[rr] + az[rr])));
        float rg  = 1.f / (1.f + __expf(-(xrv[rr] + ar[rr])));
        rh[rr]    = rg * hprev[rr];
      }
      publish2(rhcell + (t & 1) * HID, rowA, rh[0], rh[1], (unsigned)t);
    }

    // ---- exchange 2: (r*h)_t (tag t, parity t&1) ----
    {
      float2 rv = poll_pair(rhcell + (t & 1) * HID, tid, (unsigned)t, &budget);
      *(float2*)&rh_lds[2 * tid] = rv;
    }
    __syncthreads();                                   // [B2]

    float rr16[16];
    #pragma unroll
    for (int q = 0; q < 4; ++q)
      *(float4*)&rr16[q*4] = *(const float4*)&rh_lds[q * 256 + lane * 4];
    float ac[2] = {0.f, 0.f};
    #pragma unroll
    for (int rr = 0; rr < 2; ++rr)
      #pragma unroll
      for (int c = 0; c < 16; ++c)
        ac[rr] = fmaf(wgt[2][rr][c], rr16[c], ac[rr]);
    #pragma unroll
    for (int m = 1; m < 64; m <<= 1) {
      ac[0] += __shfl_xor(ac[0], m, 64);
      ac[1] += __shfl_xor(ac[1], m, 64);
    }
    if (lane == 0) {
      float hn[2];
      #pragma unroll
      for (int rr = 0; rr < 2; ++rr) {
        float cand = tanhf(xhv[rr] + ac[rr]);
        hn[rr]     = zv[rr] * hprev[rr] + (1.f - zv[rr]) * cand;
      }
      publish2(hcell + (t & 1) * HID, rowA, hn[0], hn[1], (unsigned)t);
      if (t == SEQLEN) { out[rowA] = hn[0]; out[rowA + 1] = hn[1]; }
    }
  }
}

// ---------------------------------------------------------------------------
extern "C" void kernel_launch(void* const* d_in, const int* in_sizes, int n_in,
                              void* d_out, int out_size, void* d_ws, size_t ws_size,
                              hipStream_t stream) {
  (void)in_sizes; (void)n_in; (void)out_size; (void)ws_size;

  const int*   seq = (const int*)d_in[0];
  const float* emb = (const float*)d_in[1];
  const float* Wrx = (const float*)d_in[2];
  const float* Wrh = (const float*)d_in[3];
  const float* Wzx = (const float*)d_in[4];
  const float* Wzh = (const float*)d_in[5];
  const float* Wx  = (const float*)d_in[6];
  const float* Wh  = (const float*)d_in[7];

  char* ws = (char*)d_ws;
  const size_t PROJ = (size_t)SEQLEN * HID * sizeof(float);   // 16 MB each
  float* xr    = (float*)(ws);
  float* xz    = (float*)(ws + PROJ);
  float* xh    = (float*)(ws + 2 * PROJ);
  u64*   hcell = (u64*)(ws + 3 * PROJ);                       // [2][HID]
  u64*   rhcell= hcell + 2 * HID;                             // [2][HID]

  // Tag reset every launch: 0xFFFFFFFF never matches a wanted tag in [1,4096].
  (void)hipMemsetAsync(hcell, 0xFF, 4 * HID * sizeof(u64), stream);

  proj_gemm<<<dim3(HID / 64, SEQLEN / 64, 3), 256, 0, stream>>>(
      seq, emb, Wrx, Wzx, Wx, xr, xz, xh);

  rnn_scan<<<dim3(NWG), BLOCK, 0, stream>>>(
      Wzh, Wrh, Wh, xz, xr, xh, hcell, rhcell, (float*)d_out);
}